// Round 7
// baseline (527.082 us; speedup 1.0000x reference)
//
#include <hip/hip_runtime.h>
#include <hip/hip_bf16.h>
#include <cstdint>

// VanillaLSTMCell: B=8192, I=H=1024.
// z = [x|h] @ [Wx;Wh]^T + b  (M=8192, N=4096, K=2048), LSTM pointwise fused.
//
// ROUND 11: B-direct. R10 counters showed LDS-BW-bound (71.5 B/cyc/CU = 84%
// of the 85 B/cyc ceiling; MfmaUtil 48% = exactly the MFMA duty cycle).
// Fix: B fragments load DIRECTLY global->VGPR (fragment-major = coalesced
// dwordx4; 4 waves/wn-group read identical 4KB -> L1-dedup'd), A stays
// staged via gload_lds (3 bufs x 16KB = 48KB, 2 blocks/CU, 4 waves/SIMD).
// LDS traffic 5.9 -> 3.2 GB. Depth-1 B register prefetch; manual vmcnt(6)
// at iter top guarantees A(t) landed under any compiler load reorder
// (A(t) always has >=6 younger VMEM ops). Numerics identical to R10.

typedef __bf16 bf16;
typedef __attribute__((ext_vector_type(8))) bf16 bf16x8;
typedef __attribute__((ext_vector_type(4))) float f32x4;

#define CN_OFF 8388608  // 8192*1024, c_next offset in d_out

__device__ __forceinline__ void gload16(const bf16* g, bf16* l) {
  __builtin_amdgcn_global_load_lds(
      (const __attribute__((address_space(1))) void*)g,
      (__attribute__((address_space(3))) void*)l, 16, 0, 0);
}

__device__ __forceinline__ bf16x8 cvt8(f32x4 v0, f32x4 v1) {
  bf16x8 o;
  o[0]=(bf16)v0[0]; o[1]=(bf16)v0[1]; o[2]=(bf16)v0[2]; o[3]=(bf16)v0[3];
  o[4]=(bf16)v1[0]; o[5]=(bf16)v1[1]; o[6]=(bf16)v1[2]; o[7]=(bf16)v1[3];
  return o;
}

// ---- pack: coalesced read -> LDS transpose -> coalesced fragment write ----
// A2[mb(64)][kt(64)][wm(2)][mi(4)][lane(64)][8]:
//   m = mb*128 + wm*64 + mi*16 + (lane&15), k = kt*32 + (lane>>4)*8
// B2[nb(32)][kt(64)][wn(2)][gate(4)][lane(64)][8]:
//   j = (nb*2+wn)*16 + (lane&15), k = kt*32 + (lane>>4)*8
__global__ __launch_bounds__(256) void pack_all(
    const float* __restrict__ x, const float* __restrict__ h,
    const float* __restrict__ wxi, const float* __restrict__ whi,
    const float* __restrict__ wxf, const float* __restrict__ whf,
    const float* __restrict__ wxo, const float* __restrict__ who,
    const float* __restrict__ wxg, const float* __restrict__ whg,
    const float* __restrict__ bxi, const float* __restrict__ bhi,
    const float* __restrict__ bxf, const float* __restrict__ bhf,
    const float* __restrict__ bxo, const float* __restrict__ bho,
    const float* __restrict__ bxg, const float* __restrict__ bhg,
    bf16* __restrict__ A2, bf16* __restrict__ B2, float* __restrict__ Bcomb) {
  __shared__ __align__(16) bf16 lds[8192];   // 16KB: [row][128] with XOR swizzle
  const int t = threadIdx.x;
  const int bid = blockIdx.x;

  if (bid < 2048) {
    // ---- A side ----
    const int mb = bid >> 5;
    const int wm = (bid >> 4) & 1;
    const int q  = bid & 15;                 // kt-quad: cols [q*128, q*128+128)
    const int rowbase = mb * 128 + wm * 64;
    const float* srcM; int k0;
    if (q < 8) { srcM = x; k0 = q * 128; } else { srcM = h; k0 = q * 128 - 1024; }
#pragma unroll
    for (int r = 0; r < 4; ++r) {
      const int rl = r * 16 + (t >> 4);      // 0..63
      const int cc = (t & 15) * 8;           // 0..120
      const float* s = srcM + (size_t)(rowbase + rl) * 1024 + k0 + cc;
      f32x4 v0 = *(const f32x4*)s;
      f32x4 v1 = *(const f32x4*)(s + 4);
      const int chunkS = (t & 15) ^ (rl & 7);
      *(bf16x8*)((char*)lds + rl * 256 + chunkS * 16) = cvt8(v0, v1);
    }
    __syncthreads();
#pragma unroll
    for (int r = 0; r < 4; ++r) {
      const int idx = r * 256 + t;           // 0..1023
      const int fj  = idx >> 6;              // 0..15 = ktL*4 + mi
      const int ktL = fj >> 2, mi = fj & 3;
      const int l   = idx & 63;
      const int srow = mi * 16 + (l & 15);
      const int chunkS = (ktL * 4 + (l >> 4)) ^ (srow & 7);
      bf16x8 o = *(const bf16x8*)((const char*)lds + srow * 256 + chunkS * 16);
      size_t el = ((size_t)mb * 64 + q * 4 + ktL) * 4096 + (size_t)wm * 2048 + mi * 512 + l * 8;
      *(bf16x8*)(A2 + el) = o;
    }
  } else {
    // ---- B (weights) side ----
    const int bid2 = bid - 2048;
    const int nb   = bid2 >> 6;
    const int gate = (bid2 >> 4) & 3;
    const int q    = bid2 & 15;
    const float* wxm = (gate == 0) ? wxi : (gate == 1) ? wxf : (gate == 2) ? wxo : wxg;
    const float* whm = (gate == 0) ? whi : (gate == 1) ? whf : (gate == 2) ? who : whg;
    const float* srcM; int k0;
    if (q < 8) { srcM = wxm; k0 = q * 128; } else { srcM = whm; k0 = q * 128 - 1024; }
    const int jbase = nb * 32;
#pragma unroll
    for (int r = 0; r < 2; ++r) {
      const int rl = r * 16 + (t >> 4);      // 0..31
      const int cc = (t & 15) * 8;
      const float* s = srcM + (size_t)(jbase + rl) * 1024 + k0 + cc;
      f32x4 v0 = *(const f32x4*)s;
      f32x4 v1 = *(const f32x4*)(s + 4);
      const int chunkS = (t & 15) ^ (rl & 7);
      *(bf16x8*)((char*)lds + rl * 256 + chunkS * 16) = cvt8(v0, v1);
    }
    __syncthreads();
#pragma unroll
    for (int r = 0; r < 2; ++r) {
      const int idx = r * 256 + t;           // 0..511
      const int fj  = idx >> 6;              // 0..7 = ktL*2 + wn
      const int ktL = fj >> 1, wn = fj & 1;
      const int l   = idx & 63;
      const int srow = wn * 16 + (l & 15);
      const int chunkS = (ktL * 4 + (l >> 4)) ^ (srow & 7);
      bf16x8 o = *(const bf16x8*)((const char*)lds + srow * 256 + chunkS * 16);
      size_t el = ((size_t)nb * 64 + q * 4 + ktL) * 4096 + (size_t)wn * 2048 + gate * 512 + l * 8;
      *(bf16x8*)(B2 + el) = o;
    }
    if (q == 0 && t < 32) {
      const float* bxv = (gate == 0) ? bxi : (gate == 1) ? bxf : (gate == 2) ? bxo : bxg;
      const float* bhv = (gate == 0) ? bhi : (gate == 1) ? bhf : (gate == 2) ? bho : bhg;
      const int wn = t >> 4, jl = t & 15;
      const int j = nb * 32 + wn * 16 + jl;
      Bcomb[(nb * 2 + wn) * 64 + gate * 16 + jl] = bxv[j] + bhv[j];
    }
  }
}

__device__ __forceinline__ float sigf(float v) { return 1.f / (1.f + __expf(-v)); }
__device__ __forceinline__ float tanhfast(float v) {
  v = fminf(15.f, fmaxf(-15.f, v));
  float e = __expf(2.f * v);
  return (e - 1.f) / (e + 1.f);
}

// ---- 256x128 GEMM: A via LDS (3-buf), B direct global->VGPR ----
// Block: rows [bm*256,+256), one nb unit (128 z-cols). 8 waves (wr 0..3,
// wn 0..1): wave = 64 rows x 64 z-cols, acc[4][4] f32x4 = 64 AGPR.
// Per kt: vmcnt(6) -> barrier -> stageA(kt+2) -> 4 ds_read_b128 (A) ->
// prefetch B(kt+1) to regs -> 16 MFMA on bCur -> swap.
__global__ __launch_bounds__(512, 4) void gemm_lstm(const bf16* __restrict__ A2,
                                                    const bf16* __restrict__ B2,
                                                    const float* __restrict__ Bcomb,
                                                    const float* __restrict__ c,
                                                    float* __restrict__ out) {
  __shared__ __align__(16) bf16 lds[24576];   // 48KB = 3 bufs x 8192 elems
  const int t    = threadIdx.x;
  const int wave = t >> 6;
  const int lane = t & 63;

  // XCD swizzle: xcd owns nb in [4x,4x+4) -> 2MB B2 slice L2-resident.
  const int bid = blockIdx.x;          // 1024 blocks
  const int xcd = bid & 7;
  const int idx = bid >> 3;            // 0..127
  const int nb  = xcd * 4 + (idx & 3); // 0..31
  const int bm  = idx >> 2;            // 0..31

  const int wr  = wave >> 1;           // 0..3
  const int wn  = wave & 1;            // 0..1
  const int mbU = wr >> 1, wm = wr & 1;
  const int lrow = lane & 15, lkg = lane >> 4;

  const int tEl = t * 8;               // thread's element in a 4096-elem region
  const int wEl = (t & ~63) * 8;       // wave-uniform LDS base element

  const bf16* aSrc0 = A2 + (size_t)(2 * bm)     * 64 * 4096;
  const bf16* aSrc1 = A2 + (size_t)(2 * bm + 1) * 64 * 4096;
  const bf16* bW    = B2 + (size_t)nb * 64 * 4096 + wn * 2048 + lane * 8;

  // buf layout (8192 elems): [A-mbU0: 4096][A-mbU1: 4096]
  auto stageA = [&](int tile, int buf) {
    const size_t kOff = (size_t)tile * 4096;
    bf16* d = lds + buf * 8192;
    gload16(aSrc0 + kOff + tEl, d +        wEl);
    gload16(aSrc1 + kOff + tEl, d + 4096 + wEl);
  };

  f32x4 acc[4][4] = {};   // acc[mi][gate]
  bf16x8 bCur[4], bNxt[4];

  stageA(0, 0);
  stageA(1, 1);           // 4 A-loads outstanding
#pragma unroll
  for (int g = 0; g < 4; ++g)
    bCur[g] = *(const bf16x8*)(bW + g * 512);

  const int aOff = mbU * 4096 + wm * 2048 + lane * 8;

  auto body = [&](int kt, int p, int pn, bool doStage, bool doB, bool last) {
    // A(kt) has >=6 younger VMEM ops in ANY issue order -> vmcnt(6) retires it.
    if (last) asm volatile("s_waitcnt vmcnt(0)" ::: "memory");
    else      asm volatile("s_waitcnt vmcnt(6)" ::: "memory");
    __builtin_amdgcn_s_barrier();      // => ALL waves' A(kt) staged & visible
    asm volatile("" ::: "memory");
    if (doStage) stageA(kt + 2, pn);   // overwrites buf of kt-1: consumed
                                       // (lgkm before MFMA) pre-barrier.
    const bf16* bufA = lds + p * 8192 + aOff;
    bf16x8 af[4];
#pragma unroll
    for (int i = 0; i < 4; ++i)
      af[i] = *(const bf16x8*)(bufA + i * 512);
    if (doB) {
      const bf16* bp = bW + (size_t)(kt + 1) * 4096;
#pragma unroll
      for (int g = 0; g < 4; ++g)
        bNxt[g] = *(const bf16x8*)(bp + g * 512);
    }
    __builtin_amdgcn_s_setprio(1);
#pragma unroll
    for (int mi = 0; mi < 4; ++mi)
#pragma unroll
      for (int g = 0; g < 4; ++g)
        acc[mi][g] = __builtin_amdgcn_mfma_f32_16x16x32_bf16(af[mi], bCur[g], acc[mi][g], 0, 0, 0);
    __builtin_amdgcn_s_setprio(0);
#pragma unroll
    for (int g = 0; g < 4; ++g) bCur[g] = bNxt[g];
  };

#pragma unroll 1
  for (int base = 0; base < 63; base += 3) {
    body(base,     0, 2, base     < 62, true, false);
    body(base + 1, 1, 0, base + 1 < 62, true, false);
    body(base + 2, 2, 1, base + 2 < 62, base + 2 < 63, false);
  }
  body(63, 0, 0, false, false, true);

  // ---- register-resident LSTM epilogue ----
  const int jg = (nb * 2 + wn) * 16 + lrow;
  const int bbase = (nb * 2 + wn) * 64 + lrow;
  const float bi  = Bcomb[bbase +  0];
  const float bf_ = Bcomb[bbase + 16];
  const float bo  = Bcomb[bbase + 32];
  const float bg  = Bcomb[bbase + 48];

#pragma unroll
  for (int mi = 0; mi < 4; ++mi) {
    const int row0 = bm * 256 + mbU * 128 + wm * 64 + mi * 16 + lkg * 4;
    float cv[4];
#pragma unroll
    for (int r = 0; r < 4; ++r)
      cv[r] = c[(size_t)(row0 + r) * 1024 + jg];
#pragma unroll
    for (int r = 0; r < 4; ++r) {
      float zi = acc[mi][0][r] + bi;
      float zf = acc[mi][1][r] + bf_;
      float zo = acc[mi][2][r] + bo;
      float zg = acc[mi][3][r] + bg;
      float it = sigf(zi), ft = sigf(zf), ot = sigf(zo), gt = tanhfast(zg);
      float cn = ft * cv[r] + it * gt;
      size_t off = (size_t)(row0 + r) * 1024 + jg;
      out[off] = ot * tanhfast(cn);        // h_next
      out[CN_OFF + off] = cn;              // c_next
    }
  }
}

extern "C" void kernel_launch(void* const* d_in, const int* in_sizes, int n_in,
                              void* d_out, int out_size, void* d_ws, size_t ws_size,
                              hipStream_t stream) {
  const float* x   = (const float*)d_in[0];
  const float* h   = (const float*)d_in[1];
  const float* c   = (const float*)d_in[2];
  const float* Wxi = (const float*)d_in[3];  const float* bxi = (const float*)d_in[4];
  const float* Whi = (const float*)d_in[5];  const float* bhi = (const float*)d_in[6];
  const float* Wxf = (const float*)d_in[7];  const float* bxf = (const float*)d_in[8];
  const float* Whf = (const float*)d_in[9];  const float* bhf = (const float*)d_in[10];
  const float* Wxo = (const float*)d_in[11]; const float* bxo = (const float*)d_in[12];
  const float* Who = (const float*)d_in[13]; const float* bho = (const float*)d_in[14];
  const float* Wxg = (const float*)d_in[15]; const float* bxg = (const float*)d_in[16];
  const float* Whg = (const float*)d_in[17]; const float* bhg = (const float*)d_in[18];
  float* out = (float*)d_out;

  bf16*  Abuf  = (bf16*)d_ws;                          // 32 MB
  bf16*  Wbuf  = Abuf + (size_t)8192 * 2048;           // 16 MB
  float* Bcomb = (float*)(Wbuf + (size_t)4096 * 2048); // 16 KB

  pack_all<<<4096, 256, 0, stream>>>(x, h,
                                     Wxi, Whi, Wxf, Whf, Wxo, Who, Wxg, Whg,
                                     bxi, bhi, bxf, bhf, bxo, bho, bxg, bhg,
                                     Abuf, Wbuf, Bcomb);
  gemm_lstm<<<1024, 512, 0, stream>>>(Abuf, Wbuf, Bcomb, c, out);
}

// Round 8
// 347.003 us; speedup vs baseline: 1.5190x; 1.5190x over previous
//
#include <hip/hip_runtime.h>
#include <hip/hip_bf16.h>
#include <cstdint>

// VanillaLSTMCell: B=8192, I=H=1024.
// z = [x|h] @ [Wx;Wh]^T + b  (M=8192, N=4096, K=2048), LSTM pointwise fused.
//
// ROUND 12: B-direct, register-exact. R11's 2.8x regression was a spill
// (874MB scratch writes): bNxt[4] pushed 144 > 128-reg cap. This round: B
// loads global->VGPR with NO second buffer (swap bfr LDS-dests for bCur
// global-dests = +-0 regs vs R10's exactly-128 budget). B(kt) issued BEFORE
// stageA(kt+2) so the compiler's pre-MFMA wait is vmcnt(2), never 0 -- the
// A pipeline stays in flight. LDS traffic 5.9 -> 3.2 GB (was 84% of the
// 85 B/cyc ceiling in R10 = the diagnosed limiter). Latency math: per-iter
// CU budget ~2600cy >> 200-400cy L1/L2-hit; 16 waves/CU TLP covers it.
// A staging/barrier skeleton identical to R10 (race-proven).

typedef __bf16 bf16;
typedef __attribute__((ext_vector_type(8))) bf16 bf16x8;
typedef __attribute__((ext_vector_type(4))) float f32x4;

#define CN_OFF 8388608  // 8192*1024, c_next offset in d_out

__device__ __forceinline__ void gload16(const bf16* g, bf16* l) {
  __builtin_amdgcn_global_load_lds(
      (const __attribute__((address_space(1))) void*)g,
      (__attribute__((address_space(3))) void*)l, 16, 0, 0);
}

__device__ __forceinline__ bf16x8 cvt8(f32x4 v0, f32x4 v1) {
  bf16x8 o;
  o[0]=(bf16)v0[0]; o[1]=(bf16)v0[1]; o[2]=(bf16)v0[2]; o[3]=(bf16)v0[3];
  o[4]=(bf16)v1[0]; o[5]=(bf16)v1[1]; o[6]=(bf16)v1[2]; o[7]=(bf16)v1[3];
  return o;
}

// ---- pack: coalesced read -> LDS transpose -> coalesced fragment write ----
// A2[mb(64)][kt(64)][wm(2)][mi(4)][lane(64)][8]:
//   m = mb*128 + wm*64 + mi*16 + (lane&15), k = kt*32 + (lane>>4)*8
// B2[nb(32)][kt(64)][wn(2)][gate(4)][lane(64)][8]:
//   j = (nb*2+wn)*16 + (lane&15), k = kt*32 + (lane>>4)*8
__global__ __launch_bounds__(256) void pack_all(
    const float* __restrict__ x, const float* __restrict__ h,
    const float* __restrict__ wxi, const float* __restrict__ whi,
    const float* __restrict__ wxf, const float* __restrict__ whf,
    const float* __restrict__ wxo, const float* __restrict__ who,
    const float* __restrict__ wxg, const float* __restrict__ whg,
    const float* __restrict__ bxi, const float* __restrict__ bhi,
    const float* __restrict__ bxf, const float* __restrict__ bhf,
    const float* __restrict__ bxo, const float* __restrict__ bho,
    const float* __restrict__ bxg, const float* __restrict__ bhg,
    bf16* __restrict__ A2, bf16* __restrict__ B2, float* __restrict__ Bcomb) {
  __shared__ __align__(16) bf16 lds[8192];   // 16KB: [row][128] with XOR swizzle
  const int t = threadIdx.x;
  const int bid = blockIdx.x;

  if (bid < 2048) {
    // ---- A side ----
    const int mb = bid >> 5;
    const int wm = (bid >> 4) & 1;
    const int q  = bid & 15;                 // kt-quad: cols [q*128, q*128+128)
    const int rowbase = mb * 128 + wm * 64;
    const float* srcM; int k0;
    if (q < 8) { srcM = x; k0 = q * 128; } else { srcM = h; k0 = q * 128 - 1024; }
#pragma unroll
    for (int r = 0; r < 4; ++r) {
      const int rl = r * 16 + (t >> 4);      // 0..63
      const int cc = (t & 15) * 8;           // 0..120
      const float* s = srcM + (size_t)(rowbase + rl) * 1024 + k0 + cc;
      f32x4 v0 = *(const f32x4*)s;
      f32x4 v1 = *(const f32x4*)(s + 4);
      const int chunkS = (t & 15) ^ (rl & 7);
      *(bf16x8*)((char*)lds + rl * 256 + chunkS * 16) = cvt8(v0, v1);
    }
    __syncthreads();
#pragma unroll
    for (int r = 0; r < 4; ++r) {
      const int idx = r * 256 + t;           // 0..1023
      const int fj  = idx >> 6;              // 0..15 = ktL*4 + mi
      const int ktL = fj >> 2, mi = fj & 3;
      const int l   = idx & 63;
      const int srow = mi * 16 + (l & 15);
      const int chunkS = (ktL * 4 + (l >> 4)) ^ (srow & 7);
      bf16x8 o = *(const bf16x8*)((const char*)lds + srow * 256 + chunkS * 16);
      size_t el = ((size_t)mb * 64 + q * 4 + ktL) * 4096 + (size_t)wm * 2048 + mi * 512 + l * 8;
      *(bf16x8*)(A2 + el) = o;
    }
  } else {
    // ---- B (weights) side ----
    const int bid2 = bid - 2048;
    const int nb   = bid2 >> 6;
    const int gate = (bid2 >> 4) & 3;
    const int q    = bid2 & 15;
    const float* wxm = (gate == 0) ? wxi : (gate == 1) ? wxf : (gate == 2) ? wxo : wxg;
    const float* whm = (gate == 0) ? whi : (gate == 1) ? whf : (gate == 2) ? who : whg;
    const float* srcM; int k0;
    if (q < 8) { srcM = wxm; k0 = q * 128; } else { srcM = whm; k0 = q * 128 - 1024; }
    const int jbase = nb * 32;
#pragma unroll
    for (int r = 0; r < 2; ++r) {
      const int rl = r * 16 + (t >> 4);      // 0..31
      const int cc = (t & 15) * 8;
      const float* s = srcM + (size_t)(jbase + rl) * 1024 + k0 + cc;
      f32x4 v0 = *(const f32x4*)s;
      f32x4 v1 = *(const f32x4*)(s + 4);
      const int chunkS = (t & 15) ^ (rl & 7);
      *(bf16x8*)((char*)lds + rl * 256 + chunkS * 16) = cvt8(v0, v1);
    }
    __syncthreads();
#pragma unroll
    for (int r = 0; r < 2; ++r) {
      const int idx = r * 256 + t;           // 0..511
      const int fj  = idx >> 6;              // 0..7 = ktL*2 + wn
      const int ktL = fj >> 1, wn = fj & 1;
      const int l   = idx & 63;
      const int srow = wn * 16 + (l & 15);
      const int chunkS = (ktL * 4 + (l >> 4)) ^ (srow & 7);
      bf16x8 o = *(const bf16x8*)((const char*)lds + srow * 256 + chunkS * 16);
      size_t el = ((size_t)nb * 64 + q * 4 + ktL) * 4096 + (size_t)wn * 2048 + gate * 512 + l * 8;
      *(bf16x8*)(B2 + el) = o;
    }
    if (q == 0 && t < 32) {
      const float* bxv = (gate == 0) ? bxi : (gate == 1) ? bxf : (gate == 2) ? bxo : bxg;
      const float* bhv = (gate == 0) ? bhi : (gate == 1) ? bhf : (gate == 2) ? bho : bhg;
      const int wn = t >> 4, jl = t & 15;
      const int j = nb * 32 + wn * 16 + jl;
      Bcomb[(nb * 2 + wn) * 64 + gate * 16 + jl] = bxv[j] + bhv[j];
    }
  }
}

__device__ __forceinline__ float sigf(float v) { return 1.f / (1.f + __expf(-v)); }
__device__ __forceinline__ float tanhfast(float v) {
  v = fminf(15.f, fmaxf(-15.f, v));
  float e = __expf(2.f * v);
  return (e - 1.f) / (e + 1.f);
}

// ---- 256x128 GEMM: A via LDS (3-buf, gload_lds), B direct global->VGPR ----
// Block: rows [bm*256,+256), one nb unit (128 z-cols). 8 waves (wr 0..3,
// wn 0..1): wave = 64 rows x 64 z-cols, acc[4][4] f32x4 = 64 AGPR.
// Per kt: vmcnt(2) -> barrier -> load B(kt) to regs (4 dwordx4, L1-hot) ->
// stageA(kt+2) -> 4 ds_read_b128 (A) -> 16 MFMA. Compiler's pre-MFMA wait
// for bCur is vmcnt(2) (stageA younger) -- A pipeline never drains.
__global__ __launch_bounds__(512, 4) void gemm_lstm(const bf16* __restrict__ A2,
                                                    const bf16* __restrict__ B2,
                                                    const float* __restrict__ Bcomb,
                                                    const float* __restrict__ c,
                                                    float* __restrict__ out) {
  __shared__ __align__(16) bf16 lds[24576];   // 48KB = 3 bufs x 8192 elems
  const int t    = threadIdx.x;
  const int wave = t >> 6;
  const int lane = t & 63;

  // XCD swizzle: xcd owns nb in [4x,4x+4) -> 2MB B2 slice L2-resident.
  const int bid = blockIdx.x;          // 1024 blocks
  const int xcd = bid & 7;
  const int idx = bid >> 3;            // 0..127
  const int nb  = xcd * 4 + (idx & 3); // 0..31
  const int bm  = idx >> 2;            // 0..31

  const int wr  = wave >> 1;           // 0..3
  const int wn  = wave & 1;            // 0..1
  const int mbU = wr >> 1, wm = wr & 1;
  const int lrow = lane & 15, lkg = lane >> 4;

  const int tEl = t * 8;               // thread's element in a 4096-elem region
  const int wEl = (t & ~63) * 8;       // wave-uniform LDS base element

  const bf16* aSrc0 = A2 + (size_t)(2 * bm)     * 64 * 4096;
  const bf16* aSrc1 = A2 + (size_t)(2 * bm + 1) * 64 * 4096;
  const bf16* bW    = B2 + (size_t)nb * 64 * 4096 + wn * 2048 + lane * 8;

  // buf layout (8192 elems): [A-mbU0: 4096][A-mbU1: 4096]
  auto stageA = [&](int tile, int buf) {
    const size_t kOff = (size_t)tile * 4096;
    bf16* d = lds + buf * 8192;
    gload16(aSrc0 + kOff + tEl, d +        wEl);
    gload16(aSrc1 + kOff + tEl, d + 4096 + wEl);
  };

  f32x4 acc[4][4] = {};   // acc[mi][gate]

  stageA(0, 0);
  stageA(1, 1);           // 4 A-loads outstanding

  const int aOff = mbU * 4096 + wm * 2048 + lane * 8;

  auto body = [&](int kt, int p, int pn, bool doStage, bool last) {
    // A(kt) retirement: everything older than stageA(kt+1) already retired
    // by the compiler's pre-MFMA B-wait last iter; vmcnt(2) is the safe bound.
    if (last) asm volatile("s_waitcnt vmcnt(0)" ::: "memory");
    else      asm volatile("s_waitcnt vmcnt(2)" ::: "memory");
    __builtin_amdgcn_s_barrier();      // => ALL waves' A(kt) staged & visible
    asm volatile("" ::: "memory");
    // B(kt) FIRST (so stageA is younger -> compiler waits vmcnt(2), not 0)
    const bf16* bp = bW + (size_t)kt * 4096;
    bf16x8 bCur[4];
#pragma unroll
    for (int g = 0; g < 4; ++g)
      bCur[g] = *(const bf16x8*)(bp + g * 512);
    if (doStage) stageA(kt + 2, pn);   // overwrites buf of kt-1: consumed
                                       // (lgkm before MFMA) pre-barrier.
    const bf16* bufA = lds + p * 8192 + aOff;
    bf16x8 af[4];
#pragma unroll
    for (int i = 0; i < 4; ++i)
      af[i] = *(const bf16x8*)(bufA + i * 512);
    __builtin_amdgcn_s_setprio(1);
#pragma unroll
    for (int mi = 0; mi < 4; ++mi)
#pragma unroll
      for (int g = 0; g < 4; ++g)
        acc[mi][g] = __builtin_amdgcn_mfma_f32_16x16x32_bf16(af[mi], bCur[g], acc[mi][g], 0, 0, 0);
    __builtin_amdgcn_s_setprio(0);
  };

#pragma unroll 1
  for (int base = 0; base < 63; base += 3) {
    body(base,     0, 2, base     < 62, false);
    body(base + 1, 1, 0, base + 1 < 62, false);
    body(base + 2, 2, 1, base + 2 < 62, false);
  }
  body(63, 0, 0, false, true);

  // ---- register-resident LSTM epilogue ----
  const int jg = (nb * 2 + wn) * 16 + lrow;
  const int bbase = (nb * 2 + wn) * 64 + lrow;
  const float bi  = Bcomb[bbase +  0];
  const float bf_ = Bcomb[bbase + 16];
  const float bo  = Bcomb[bbase + 32];
  const float bg  = Bcomb[bbase + 48];

#pragma unroll
  for (int mi = 0; mi < 4; ++mi) {
    const int row0 = bm * 256 + mbU * 128 + wm * 64 + mi * 16 + lkg * 4;
    float cv[4];
#pragma unroll
    for (int r = 0; r < 4; ++r)
      cv[r] = c[(size_t)(row0 + r) * 1024 + jg];
#pragma unroll
    for (int r = 0; r < 4; ++r) {
      float zi = acc[mi][0][r] + bi;
      float zf = acc[mi][1][r] + bf_;
      float zo = acc[mi][2][r] + bo;
      float zg = acc[mi][3][r] + bg;
      float it = sigf(zi), ft = sigf(zf), ot = sigf(zo), gt = tanhfast(zg);
      float cn = ft * cv[r] + it * gt;
      size_t off = (size_t)(row0 + r) * 1024 + jg;
      out[off] = ot * tanhfast(cn);        // h_next
      out[CN_OFF + off] = cn;              // c_next
    }
  }
}

extern "C" void kernel_launch(void* const* d_in, const int* in_sizes, int n_in,
                              void* d_out, int out_size, void* d_ws, size_t ws_size,
                              hipStream_t stream) {
  const float* x   = (const float*)d_in[0];
  const float* h   = (const float*)d_in[1];
  const float* c   = (const float*)d_in[2];
  const float* Wxi = (const float*)d_in[3];  const float* bxi = (const float*)d_in[4];
  const float* Whi = (const float*)d_in[5];  const float* bhi = (const float*)d_in[6];
  const float* Wxf = (const float*)d_in[7];  const float* bxf = (const float*)d_in[8];
  const float* Whf = (const float*)d_in[9];  const float* bhf = (const float*)d_in[10];
  const float* Wxo = (const float*)d_in[11]; const float* bxo = (const float*)d_in[12];
  const float* Who = (const float*)d_in[13]; const float* bho = (const float*)d_in[14];
  const float* Wxg = (const float*)d_in[15]; const float* bxg = (const float*)d_in[16];
  const float* Whg = (const float*)d_in[17]; const float* bhg = (const float*)d_in[18];
  float* out = (float*)d_out;

  bf16*  Abuf  = (bf16*)d_ws;                          // 32 MB
  bf16*  Wbuf  = Abuf + (size_t)8192 * 2048;           // 16 MB
  float* Bcomb = (float*)(Wbuf + (size_t)4096 * 2048); // 16 KB

  pack_all<<<4096, 256, 0, stream>>>(x, h,
                                     Wxi, Whi, Wxf, Whf, Wxo, Who, Wxg, Whg,
                                     bxi, bhi, bxf, bhf, bxo, bho, bxg, bhg,
                                     Abuf, Wbuf, Bcomb);
  gemm_lstm<<<1024, 512, 0, stream>>>(Abuf, Wbuf, Bcomb, c, out);
}